// Round 4
// baseline (6229.551 us; speedup 1.0000x reference)
//
#include <hip/hip_runtime.h>
#include <cstdint>
#include <cstddef>

// Problem constants
#define B_   64
#define S_   512
#define ISZ  256
#define HSZ  512
#define NG   2048    // 4*H

typedef unsigned short u16;
typedef __attribute__((ext_vector_type(8))) short short8;
typedef __attribute__((ext_vector_type(4))) float floatx4;

// Workspace layout (bytes)
static const size_t OFF_WPACK = 0;                        // 2*2048*768*2 = 6,291,456
static const size_t OFF_XB    = 6291456;                  // 512*64*256*2 = 16,777,216
static const size_t OFF_HB    = OFF_XB + 16777216;        // 2 par * 2 dir * 64 * 512 * 2B = 262,144
static const size_t OFF_FLAGS = OFF_HB + 262144;          // 8 chains * 512 steps * 32 * 4B = 524,288

__device__ __forceinline__ u16 f2bf(float f) {
    uint32_t u = __float_as_uint(f);
    return (u16)((u + 0x7fffu + ((u >> 16) & 1u)) >> 16);  // RNE
}
__device__ __forceinline__ float sigmoidf_(float x) {
    return 1.0f / (1.0f + __expf(-x));
}
__device__ __forceinline__ float tanhf_(float x) {
    return 1.0f - 2.0f / (__expf(2.0f * x) + 1.0f);
}

// ---------------------------------------------------------------------------
// Pack W_f / W_b (768 x 2048 f32, row-major) into bf16 MFMA-B-fragment order,
// gate-interleaved per 16-hidden-unit chunk:
//   flat = ((dir*128 + nb)*24 + kb)*512 + lane*8 + j
// ---------------------------------------------------------------------------
__global__ __launch_bounds__(256) void pack_w(const float* __restrict__ Wf,
                                              const float* __restrict__ Wb,
                                              u16* __restrict__ wpack) {
    int tid = blockIdx.x * 256 + threadIdx.x;   // over 768*2048
    int dir = blockIdx.y;
    int p = tid & 2047;
    int k = tid >> 11;
    int gate = (p >> 4) & 3;
    int hid  = (p >> 6) * 16 + (p & 15);
    int col  = gate * HSZ + hid;
    const float* W = dir ? Wb : Wf;
    float v = W[(size_t)k * NG + col];
    int nb   = p >> 4;
    int lane = ((k & 31) >> 3) * 16 + (p & 15);
    size_t idx = (((size_t)(dir * 128 + nb) * 24 + (k >> 5)) * 512) + lane * 8 + (k & 7);
    wpack[idx] = f2bf(v);
}

// inputs (B,S,I) f32 -> Xb [t][b][i] bf16
__global__ __launch_bounds__(256) void pack_x(const float* __restrict__ x,
                                              u16* __restrict__ xb) {
    int tid = blockIdx.x * 256 + threadIdx.x;   // over S*B*I = 8,388,608
    int i = tid & 255;
    int b = (tid >> 8) & 63;
    int t = tid >> 14;
    xb[tid] = f2bf(x[((size_t)b * S_ + t) * ISZ + i]);
}

// ---------------------------------------------------------------------------
// Persistent BiLSTM kernel, flag-based sync (no counter RMW barrier).
// grid = 256 x 128 (2 waves). chain = blockIdx&7 (dir,bg); c = blockIdx>>3.
// Per step: x-part MFMAs (independent) -> poll 32 producer flags of step t-1
// (lane-parallel + ballot) -> h-part MFMAs -> LDS gate exchange -> cell update
// -> store h to parity buffer -> flag store -> deferred out atomicAdds.
// ---------------------------------------------------------------------------
__global__ __launch_bounds__(128, 1) void bilstm_persistent(
    const u16* __restrict__ wpack, const u16* __restrict__ xb,
    u16* __restrict__ hbuf, int* __restrict__ flags,
    const float* __restrict__ bf_, const float* __restrict__ bb_,
    float* __restrict__ out)
{
    const int tid = threadIdx.x;
    const int l   = tid & 63;
    const int lm  = l & 15;
    const int lq  = l >> 4;
    const int gp  = tid >> 6;            // 0: gates f,i ; 1: gates o,g
    const int chain = blockIdx.x & 7;
    const int c     = blockIdx.x >> 3;
    const int dir   = chain >> 2;
    const int bg    = chain & 3;

    __shared__ float gsm[4][16][20];     // [gate][hid_l][batch_l(+pad)]

    // W fragment base for this wave (2 N-tiles), streamed from L2 each step.
    const u16* wbase = wpack + ((size_t)(dir * 128 + c * 4 + gp * 2) * 24) * 512 + l * 8;

    // epilogue cell assignment
    const int hid_l = tid >> 3;          // 0..15
    const int bl0   = (tid & 7) * 2;     // batches bl0, bl0+1
    const int hid   = c * 16 + hid_l;
    const float* bias = dir ? bb_ : bf_;
    const float Bf = bias[hid];
    const float Bi = bias[HSZ + hid];
    const float Bo = bias[2 * HSZ + hid];
    const float Bg = bias[3 * HSZ + hid];
    float cprev0 = 0.0f, cprev1 = 0.0f;

    const u16* abx = xb + ((size_t)(bg * 16 + lm)) * ISZ + lq * 8;   // + tx*64*ISZ

    for (int t = 0; t < S_; ++t) {
        const int tx = dir ? (S_ - 1 - t) : t;

        floatx4 acc0 = (floatx4){0.f, 0.f, 0.f, 0.f};
        floatx4 acc1 = (floatx4){0.f, 0.f, 0.f, 0.f};

        // ---- x-part (independent of recurrence; overlaps producer stragglers)
        const u16* ax = abx + (size_t)tx * (64 * ISZ);
#pragma unroll
        for (int kb = 0; kb < 8; ++kb) {
            short8 a  = *(const short8*)(ax + kb * 32);
            short8 w0 = *(const short8*)(wbase + (size_t)(0 * 24 + kb) * 512);
            short8 w1 = *(const short8*)(wbase + (size_t)(1 * 24 + kb) * 512);
            acc0 = __builtin_amdgcn_mfma_f32_16x16x32_bf16(a, w0, acc0, 0, 0, 0);
            acc1 = __builtin_amdgcn_mfma_f32_16x16x32_bf16(a, w1, acc1, 0, 0, 0);
        }

        // ---- wait for h(t): all 32 producer flags of step t-1 ----
        if (t > 0) {
            const int* fl = flags + ((size_t)chain * S_ + (t - 1)) * 32;
            for (;;) {
                int v = __hip_atomic_load(&fl[l & 31], __ATOMIC_RELAXED,
                                          __HIP_MEMORY_SCOPE_AGENT);
                if (__ballot(v != 0) == ~0ull) break;
                __builtin_amdgcn_s_sleep(1);
            }
            __builtin_amdgcn_fence(__ATOMIC_ACQUIRE, "agent");
        }

        // ---- h-part: read h from parity buffer t&1 ----
        const u16* ah = hbuf + ((size_t)((t & 1) * 2 + dir) * 64 + bg * 16 + lm) * HSZ + lq * 8;
#pragma unroll
        for (int kb = 0; kb < 16; ++kb) {
            short8 a  = *(const short8*)(ah + kb * 32);
            short8 w0 = *(const short8*)(wbase + (size_t)(0 * 24 + 8 + kb) * 512);
            short8 w1 = *(const short8*)(wbase + (size_t)(1 * 24 + 8 + kb) * 512);
            acc0 = __builtin_amdgcn_mfma_f32_16x16x32_bf16(a, w0, acc0, 0, 0, 0);
            acc1 = __builtin_amdgcn_mfma_f32_16x16x32_bf16(a, w1, acc1, 0, 0, 0);
        }

        // ---- gate exchange via LDS ----
#pragma unroll
        for (int r = 0; r < 4; ++r) {
            gsm[gp * 2 + 0][lm][lq * 4 + r] = acc0[r];
            gsm[gp * 2 + 1][lm][lq * 4 + r] = acc1[r];
        }
        __syncthreads();

        // ---- cell update (2 cells/thread, c-state in registers) ----
        float f0 = gsm[0][hid_l][bl0]     + Bf;
        float i0 = gsm[1][hid_l][bl0]     + Bi;
        float o0 = gsm[2][hid_l][bl0]     + Bo;
        float g0 = gsm[3][hid_l][bl0]     + Bg;
        float f1 = gsm[0][hid_l][bl0 + 1] + Bf;
        float i1 = gsm[1][hid_l][bl0 + 1] + Bi;
        float o1 = gsm[2][hid_l][bl0 + 1] + Bo;
        float g1 = gsm[3][hid_l][bl0 + 1] + Bg;
        float cn0 = sigmoidf_(f0) * cprev0 + sigmoidf_(i0) * tanhf_(g0);
        float cn1 = sigmoidf_(f1) * cprev1 + sigmoidf_(i1) * tanhf_(g1);
        float h0 = sigmoidf_(o0) * tanhf_(cn0);
        float h1 = sigmoidf_(o1) * tanhf_(cn1);
        cprev0 = cn0; cprev1 = cn1;

        const int b0 = bg * 16 + bl0;

        // ---- store new h to parity buffer (t+1)&1 ----
        u16* hw = hbuf + ((size_t)(((t + 1) & 1) * 2 + dir) * 64) * HSZ;
        hw[(size_t)b0 * HSZ + hid]       = f2bf(h0);
        hw[(size_t)(b0 + 1) * HSZ + hid] = f2bf(h1);

        __syncthreads();   // drains both waves' h stores (vmcnt(0) before s_barrier)

        // ---- signal: this block's h(t+1) chunk is visible ----
        if (tid == 0) {
            __builtin_amdgcn_fence(__ATOMIC_RELEASE, "agent");
            __hip_atomic_store(&flags[((size_t)chain * S_ + t) * 32 + c], 1,
                               __ATOMIC_RELAXED, __HIP_MEMORY_SCOPE_AGENT);
        }

        // ---- deferred output accumulation (off critical path) ----
        atomicAdd(&out[((size_t)b0 * S_ + tx) * HSZ + hid],       0.5f * h0);
        atomicAdd(&out[((size_t)(b0 + 1) * S_ + tx) * HSZ + hid], 0.5f * h1);
    }
}

extern "C" void kernel_launch(void* const* d_in, const int* in_sizes, int n_in,
                              void* d_out, int out_size, void* d_ws, size_t ws_size,
                              hipStream_t stream) {
    const float* x  = (const float*)d_in[0];
    const float* Wf = (const float*)d_in[1];
    const float* bf = (const float*)d_in[2];
    const float* Wb = (const float*)d_in[3];
    const float* bb = (const float*)d_in[4];
    float* out = (float*)d_out;
    char* ws = (char*)d_ws;

    u16*   wpack = (u16*)(ws + OFF_WPACK);
    u16*   xb    = (u16*)(ws + OFF_XB);
    u16*   hbuf  = (u16*)(ws + OFF_HB);
    int*   flags = (int*)(ws + OFF_FLAGS);

    // zero h parity buffers + flags (contiguous), and the output (accumulated)
    (void)hipMemsetAsync(ws + OFF_HB, 0, 262144 + 524288, stream);
    (void)hipMemsetAsync(d_out, 0, (size_t)out_size * sizeof(float), stream);

    pack_w<<<dim3(6144, 2), 256, 0, stream>>>(Wf, Wb, wpack);
    pack_x<<<dim3(32768), 256, 0, stream>>>(x, xb);

    bilstm_persistent<<<dim3(256), dim3(128), 0, stream>>>(
        wpack, xb, hbuf, flags, bf, bb, out);
}

// Round 5
// 5212.838 us; speedup vs baseline: 1.1950x; 1.1950x over previous
//
#include <hip/hip_runtime.h>
#include <cstdint>
#include <cstddef>

// Problem constants
#define B_   64
#define S_   512
#define ISZ  256
#define HSZ  512
#define NG   2048    // 4*H

typedef unsigned short u16;
typedef __attribute__((ext_vector_type(8))) short short8;
typedef __attribute__((ext_vector_type(4))) float floatx4;

// Workspace layout (bytes), total ~57.4 MB
static const size_t OFF_WPACK = 0;                        // 2*2048*768*2 = 6,291,456
static const size_t OFF_XB    = 6291456;                  // 512*64*256*2 = 16,777,216
static const size_t OFF_HB    = OFF_XB + 16777216;        // 2 parity * 2 dir * 64 * 512 * 2B = 262,144
static const size_t OFF_FLAGS = OFF_HB + 262144;          // 8 chains * 512 steps * 32 * 4B = 524,288
static const size_t OFF_STAGE = OFF_FLAGS + 524288;       // 512*64*512*2B = 33,554,432 (bwd h, bf16)

__device__ __forceinline__ u16 f2bf(float f) {
    uint32_t u = __float_as_uint(f);
    return (u16)((u + 0x7fffu + ((u >> 16) & 1u)) >> 16);  // RNE
}
__device__ __forceinline__ float sigmoidf_(float x) {
    return 1.0f / (1.0f + __expf(-x));
}
__device__ __forceinline__ float tanhf_(float x) {
    return 1.0f - 2.0f / (__expf(2.0f * x) + 1.0f);
}

// ---------------------------------------------------------------------------
// Pack W_f / W_b (768 x 2048 f32, row-major) into bf16 MFMA-B-fragment order,
// gate-interleaved per 16-hidden-unit chunk:
//   flat = ((dir*128 + nb)*24 + kb)*512 + lane*8 + j ;  nb = 4c+gate
// ---------------------------------------------------------------------------
__global__ __launch_bounds__(256) void pack_w(const float* __restrict__ Wf,
                                              const float* __restrict__ Wb,
                                              u16* __restrict__ wpack) {
    int tid = blockIdx.x * 256 + threadIdx.x;   // over 768*2048
    int dir = blockIdx.y;
    int p = tid & 2047;
    int k = tid >> 11;
    int gate = (p >> 4) & 3;
    int hid  = (p >> 6) * 16 + (p & 15);
    int col  = gate * HSZ + hid;
    const float* W = dir ? Wb : Wf;
    float v = W[(size_t)k * NG + col];
    int nb   = p >> 4;
    int lane = ((k & 31) >> 3) * 16 + (p & 15);
    size_t idx = (((size_t)(dir * 128 + nb) * 24 + (k >> 5)) * 512) + lane * 8 + (k & 7);
    wpack[idx] = f2bf(v);
}

// inputs (B,S,I) f32 -> Xb [t][b][i] bf16
__global__ __launch_bounds__(256) void pack_x(const float* __restrict__ x,
                                              u16* __restrict__ xb) {
    int tid = blockIdx.x * 256 + threadIdx.x;   // over S*B*I = 8,388,608
    int i = tid & 255;
    int b = (tid >> 8) & 63;
    int t = tid >> 14;
    xb[tid] = f2bf(x[((size_t)b * S_ + t) * ISZ + i]);
}

// ---------------------------------------------------------------------------
// Persistent BiLSTM. grid = 256 blocks x 64 threads (ONE wave per block).
//   chain = blockIdx&7 (dir = chain>>2, bg = chain&3), c = blockIdx>>3.
// One wave computes ALL 4 gates (4 MFMA accumulators) for 16 batches x 16 hid.
// C-layout (col=lane&15=hid_l, row=lq*4+r=batch_l) means each lane holds all 4
// gates of its 4 cells -> no cross-wave exchange, no in-loop __syncthreads.
// h-part W (64 KB) lives in LDS; x-part W streams from L2 before the poll.
// fwd stores 0.5*h to out (plain f32); bwd stages h bf16; combine adds halves.
// ---------------------------------------------------------------------------
__global__ __launch_bounds__(64, 1) void bilstm_persistent(
    const u16* __restrict__ wpack, const u16* __restrict__ xb,
    u16* __restrict__ hbuf, int* __restrict__ flags,
    const float* __restrict__ bf_, const float* __restrict__ bb_,
    float* __restrict__ out, u16* __restrict__ stage)
{
    const int l  = threadIdx.x;
    const int lm = l & 15;
    const int lq = l >> 4;
    const int chain = blockIdx.x & 7;
    const int c     = blockIdx.x >> 3;
    const int dir   = chain >> 2;
    const int bg    = chain & 3;

    __shared__ u16 wlds[4 * 16 * 512];   // 65536 B: h-part W, [(g*16+kh)*512 + lane*8 + j]

    // ---- stage h-part W into LDS (once): wpack kb 8..23 of tiles 4c..4c+3 ----
#pragma unroll
    for (int g = 0; g < 4; ++g)
        for (int kh = 0; kh < 16; ++kh) {
            const u16* src = wpack + ((size_t)(dir * 128 + c * 4 + g) * 24 + 8 + kh) * 512 + l * 8;
            *(short8*)&wlds[(g * 16 + kh) * 512 + l * 8] = *(const short8*)src;
        }
    __syncthreads();

    const int hid = c * 16 + lm;
    const float* bias = dir ? bb_ : bf_;
    const float Bf = bias[hid];
    const float Bi = bias[HSZ + hid];
    const float Bo = bias[2 * HSZ + hid];
    const float Bg = bias[3 * HSZ + hid];
    float cst[4] = {0.f, 0.f, 0.f, 0.f};

    const u16* abx = xb + ((size_t)(bg * 16 + lm)) * ISZ + lq * 8;   // + tx*B_*ISZ
    const u16* wx  = wpack + ((size_t)(dir * 128 + c * 4) * 24) * 512 + l * 8;  // +(g*24+kb)*512

    for (int t = 0; t < S_; ++t) {
        const int tx = dir ? (S_ - 1 - t) : t;

        floatx4 acc0 = (floatx4){0.f, 0.f, 0.f, 0.f};
        floatx4 acc1 = (floatx4){0.f, 0.f, 0.f, 0.f};
        floatx4 acc2 = (floatx4){0.f, 0.f, 0.f, 0.f};
        floatx4 acc3 = (floatx4){0.f, 0.f, 0.f, 0.f};

        // ---- x-part (recurrence-independent; W streams from L2, latency hidden)
        const u16* ax = abx + (size_t)tx * (B_ * ISZ);
#pragma unroll
        for (int kb = 0; kb < 8; ++kb) {
            short8 a  = *(const short8*)(ax + kb * 32);
            short8 w0 = *(const short8*)(wx + (size_t)(0 * 24 + kb) * 512);
            short8 w1 = *(const short8*)(wx + (size_t)(1 * 24 + kb) * 512);
            short8 w2 = *(const short8*)(wx + (size_t)(2 * 24 + kb) * 512);
            short8 w3 = *(const short8*)(wx + (size_t)(3 * 24 + kb) * 512);
            acc0 = __builtin_amdgcn_mfma_f32_16x16x32_bf16(a, w0, acc0, 0, 0, 0);
            acc1 = __builtin_amdgcn_mfma_f32_16x16x32_bf16(a, w1, acc1, 0, 0, 0);
            acc2 = __builtin_amdgcn_mfma_f32_16x16x32_bf16(a, w2, acc2, 0, 0, 0);
            acc3 = __builtin_amdgcn_mfma_f32_16x16x32_bf16(a, w3, acc3, 0, 0, 0);
        }

        // ---- wait for h(t): 32 producer flags of step t-1, one coalesced load/iter
        if (t > 0) {
            const int* fl = flags + ((size_t)chain * S_ + (t - 1)) * 32;
            for (;;) {
                int v = __hip_atomic_load(&fl[l & 31], __ATOMIC_RELAXED,
                                          __HIP_MEMORY_SCOPE_AGENT);
                if (__ballot(v != 0) == ~0ull) break;
                __builtin_amdgcn_s_sleep(1);
            }
            __builtin_amdgcn_fence(__ATOMIC_ACQUIRE, "agent");
        }

        // ---- h-part: h from parity buffer (t&1), W from LDS ----
        const u16* ah = hbuf + ((size_t)((t & 1) * 2 + dir) * B_ + bg * 16 + lm) * HSZ + lq * 8;
#pragma unroll
        for (int kb = 0; kb < 16; ++kb) {
            short8 a  = *(const short8*)(ah + kb * 32);
            short8 w0 = *(const short8*)&wlds[(0 * 16 + kb) * 512 + l * 8];
            short8 w1 = *(const short8*)&wlds[(1 * 16 + kb) * 512 + l * 8];
            short8 w2 = *(const short8*)&wlds[(2 * 16 + kb) * 512 + l * 8];
            short8 w3 = *(const short8*)&wlds[(3 * 16 + kb) * 512 + l * 8];
            acc0 = __builtin_amdgcn_mfma_f32_16x16x32_bf16(a, w0, acc0, 0, 0, 0);
            acc1 = __builtin_amdgcn_mfma_f32_16x16x32_bf16(a, w1, acc1, 0, 0, 0);
            acc2 = __builtin_amdgcn_mfma_f32_16x16x32_bf16(a, w2, acc2, 0, 0, 0);
            acc3 = __builtin_amdgcn_mfma_f32_16x16x32_bf16(a, w3, acc3, 0, 0, 0);
        }

        // ---- cell update: lane l owns batches bg*16+lq*4+r, hid = c*16+lm ----
        u16* hw = hbuf + ((size_t)(((t + 1) & 1) * 2 + dir) * B_) * HSZ;
        float hv[4];
#pragma unroll
        for (int r = 0; r < 4; ++r) {
            float fg = acc0[r] + Bf;
            float ig = acc1[r] + Bi;
            float og = acc2[r] + Bo;
            float gg = acc3[r] + Bg;
            float cn = sigmoidf_(fg) * cst[r] + sigmoidf_(ig) * tanhf_(gg);
            float hn = sigmoidf_(og) * tanhf_(cn);
            cst[r] = cn;
            hv[r] = hn;
            hw[(size_t)(bg * 16 + lq * 4 + r) * HSZ + hid] = f2bf(hn);
        }

        // ---- release h stores, then signal ----
        __builtin_amdgcn_fence(__ATOMIC_RELEASE, "agent");
        if (l == 0)
            __hip_atomic_store(&flags[((size_t)chain * S_ + t) * 32 + c], 1,
                               __ATOMIC_RELAXED, __HIP_MEMORY_SCOPE_AGENT);

        // ---- deferred output (off critical path; plain stores, no atomics) ----
#pragma unroll
        for (int r = 0; r < 4; ++r) {
            const int b = bg * 16 + lq * 4 + r;
            const size_t oidx = ((size_t)b * S_ + tx) * HSZ + hid;
            if (dir == 0) out[oidx] = 0.5f * hv[r];
            else          stage[oidx] = f2bf(hv[r]);
        }
    }
}

// out[i] += 0.5 * bf16(stage[i]); 4 elems/thread
__global__ __launch_bounds__(256) void combine(float* __restrict__ out,
                                               const u16* __restrict__ stage) {
    int i = (blockIdx.x * 256 + threadIdx.x) * 4;   // over 16,777,216
    ushort4 s = *(const ushort4*)(stage + i);
    float4 o = *(float4*)(out + i);
    o.x += 0.5f * __uint_as_float((uint32_t)s.x << 16);
    o.y += 0.5f * __uint_as_float((uint32_t)s.y << 16);
    o.z += 0.5f * __uint_as_float((uint32_t)s.z << 16);
    o.w += 0.5f * __uint_as_float((uint32_t)s.w << 16);
    *(float4*)(out + i) = o;
}

extern "C" void kernel_launch(void* const* d_in, const int* in_sizes, int n_in,
                              void* d_out, int out_size, void* d_ws, size_t ws_size,
                              hipStream_t stream) {
    const float* x  = (const float*)d_in[0];
    const float* Wf = (const float*)d_in[1];
    const float* bf = (const float*)d_in[2];
    const float* Wb = (const float*)d_in[3];
    const float* bb = (const float*)d_in[4];
    float* out = (float*)d_out;
    char* ws = (char*)d_ws;

    u16*   wpack = (u16*)(ws + OFF_WPACK);
    u16*   xb    = (u16*)(ws + OFF_XB);
    u16*   hbuf  = (u16*)(ws + OFF_HB);
    int*   flags = (int*)(ws + OFF_FLAGS);
    u16*   stage = (u16*)(ws + OFF_STAGE);

    // zero h parity buffers + flags (contiguous)
    (void)hipMemsetAsync(ws + OFF_HB, 0, 262144 + 524288, stream);

    pack_w<<<dim3(6144, 2), 256, 0, stream>>>(Wf, Wb, wpack);
    pack_x<<<dim3(32768), 256, 0, stream>>>(x, xb);

    bilstm_persistent<<<dim3(256), dim3(64), 0, stream>>>(
        wpack, xb, hbuf, flags, bf, bb, out, stage);

    combine<<<dim3(16384), 256, 0, stream>>>(out, stage);
}

// Round 6
// 3420.578 us; speedup vs baseline: 1.8212x; 1.5240x over previous
//
#include <hip/hip_runtime.h>
#include <cstdint>
#include <cstddef>

// Problem constants
#define B_   64
#define S_   512
#define ISZ  256
#define HSZ  512
#define NG   2048    // 4*H

typedef unsigned short u16;
typedef unsigned long long u64;
typedef __attribute__((ext_vector_type(8))) short short8;
typedef __attribute__((ext_vector_type(4))) float floatx4;

// Workspace layout (bytes), total ~57.4 MB
static const size_t OFF_WPACK = 0;                        // 2*2048*768*2 = 6,291,456
static const size_t OFF_XB    = 6291456;                  // 512*64*256*2 = 16,777,216
static const size_t OFF_HB    = OFF_XB + 16777216;        // 2 parity * 2 dir * 64 * 512 * 2B = 262,144
static const size_t OFF_FLAGS = OFF_HB + 262144;          // 8 chains * 512 steps * 32 * 4B = 524,288
static const size_t OFF_STAGE = OFF_FLAGS + 524288;       // 512*64*512*2B = 33,554,432 (bwd h, bf16)

__device__ __forceinline__ u16 f2bf(float f) {
    uint32_t u = __float_as_uint(f);
    return (u16)((u + 0x7fffu + ((u >> 16) & 1u)) >> 16);  // RNE
}
__device__ __forceinline__ float sigmoidf_(float x) {
    return 1.0f / (1.0f + __expf(-x));
}
__device__ __forceinline__ float tanhf_(float x) {
    return 1.0f - 2.0f / (__expf(2.0f * x) + 1.0f);
}

// ---------------------------------------------------------------------------
// Pack W_f / W_b (768 x 2048 f32, row-major) into bf16 MFMA-B-fragment order,
// gate-interleaved per 16-hidden-unit chunk:
//   flat = ((dir*128 + nb)*24 + kb)*512 + lane*8 + j ;  nb = 4c+gate
// ---------------------------------------------------------------------------
__global__ __launch_bounds__(256) void pack_w(const float* __restrict__ Wf,
                                              const float* __restrict__ Wb,
                                              u16* __restrict__ wpack) {
    int tid = blockIdx.x * 256 + threadIdx.x;   // over 768*2048
    int dir = blockIdx.y;
    int p = tid & 2047;
    int k = tid >> 11;
    int gate = (p >> 4) & 3;
    int hid  = (p >> 6) * 16 + (p & 15);
    int col  = gate * HSZ + hid;
    const float* W = dir ? Wb : Wf;
    float v = W[(size_t)k * NG + col];
    int nb   = p >> 4;
    int lane = ((k & 31) >> 3) * 16 + (p & 15);
    size_t idx = (((size_t)(dir * 128 + nb) * 24 + (k >> 5)) * 512) + lane * 8 + (k & 7);
    wpack[idx] = f2bf(v);
}

// inputs (B,S,I) f32 -> Xb [t][b][i] bf16
__global__ __launch_bounds__(256) void pack_x(const float* __restrict__ x,
                                              u16* __restrict__ xb) {
    int tid = blockIdx.x * 256 + threadIdx.x;   // over S*B*I = 8,388,608
    int i = tid & 255;
    int b = (tid >> 8) & 63;
    int t = tid >> 14;
    xb[tid] = f2bf(x[((size_t)b * S_ + t) * ISZ + i]);
}

// ---------------------------------------------------------------------------
// Persistent BiLSTM. grid = 256 blocks x 64 threads (one wave per block).
//   chain = blockIdx&7 (dir = chain>>2, bg = chain&3), c = blockIdx>>3.
// FENCE-FREE cross-block handshake (the R3-R5 fences lowered to per-step L2
// writeback/invalidate walks -- the ~8us/step floor):
//   producer: relaxed agent atomic h stores (write-through to L3)
//             -> asm s_waitcnt vmcnt(0) (h acks at coherent point)
//             -> relaxed agent atomic flag store
//   consumer: relaxed agent atomic flag poll -> compiler barrier
//             -> relaxed agent atomic h loads (bypass L1/L2, always fresh)
// ---------------------------------------------------------------------------
__global__ __launch_bounds__(64, 1) void bilstm_persistent(
    const u16* __restrict__ wpack, const u16* __restrict__ xb,
    u16* __restrict__ hbuf, int* __restrict__ flags,
    const float* __restrict__ bf_, const float* __restrict__ bb_,
    float* __restrict__ out, u16* __restrict__ stage)
{
    const int l  = threadIdx.x;
    const int lm = l & 15;
    const int lq = l >> 4;
    const int chain = blockIdx.x & 7;
    const int c     = blockIdx.x >> 3;
    const int dir   = chain >> 2;
    const int bg    = chain & 3;

    __shared__ u16 wlds[4 * 16 * 512];   // 65536 B: h-part W, [(g*16+kh)*512 + lane*8 + j]

    // ---- stage h-part W into LDS (once) ----
#pragma unroll
    for (int g = 0; g < 4; ++g)
        for (int kh = 0; kh < 16; ++kh) {
            const u16* src = wpack + ((size_t)(dir * 128 + c * 4 + g) * 24 + 8 + kh) * 512 + l * 8;
            *(short8*)&wlds[(g * 16 + kh) * 512 + l * 8] = *(const short8*)src;
        }
    __syncthreads();

    const int hid = c * 16 + lm;
    const float* bias = dir ? bb_ : bf_;
    const float Bf = bias[hid];
    const float Bi = bias[HSZ + hid];
    const float Bo = bias[2 * HSZ + hid];
    const float Bg = bias[3 * HSZ + hid];
    float cst[4] = {0.f, 0.f, 0.f, 0.f};

    const u16* abx = xb + ((size_t)(bg * 16 + lm)) * ISZ + lq * 8;   // + tx*B_*ISZ
    const u16* wx  = wpack + ((size_t)(dir * 128 + c * 4) * 24) * 512 + l * 8;  // +(g*24+kb)*512

    for (int t = 0; t < S_; ++t) {
        const int tx = dir ? (S_ - 1 - t) : t;

        floatx4 acc0 = (floatx4){0.f, 0.f, 0.f, 0.f};
        floatx4 acc1 = (floatx4){0.f, 0.f, 0.f, 0.f};
        floatx4 acc2 = (floatx4){0.f, 0.f, 0.f, 0.f};
        floatx4 acc3 = (floatx4){0.f, 0.f, 0.f, 0.f};

        // ---- x-part (recurrence-independent; W streams from L2, latency hidden)
        const u16* ax = abx + (size_t)tx * (B_ * ISZ);
#pragma unroll
        for (int kb = 0; kb < 8; ++kb) {
            short8 a  = *(const short8*)(ax + kb * 32);
            short8 w0 = *(const short8*)(wx + (size_t)(0 * 24 + kb) * 512);
            short8 w1 = *(const short8*)(wx + (size_t)(1 * 24 + kb) * 512);
            short8 w2 = *(const short8*)(wx + (size_t)(2 * 24 + kb) * 512);
            short8 w3 = *(const short8*)(wx + (size_t)(3 * 24 + kb) * 512);
            acc0 = __builtin_amdgcn_mfma_f32_16x16x32_bf16(a, w0, acc0, 0, 0, 0);
            acc1 = __builtin_amdgcn_mfma_f32_16x16x32_bf16(a, w1, acc1, 0, 0, 0);
            acc2 = __builtin_amdgcn_mfma_f32_16x16x32_bf16(a, w2, acc2, 0, 0, 0);
            acc3 = __builtin_amdgcn_mfma_f32_16x16x32_bf16(a, w3, acc3, 0, 0, 0);
        }

        // ---- wait for h(t): 32 producer flags of step t-1, relaxed poll ----
        if (t > 0) {
            const int* fl = flags + ((size_t)chain * S_ + (t - 1)) * 32;
            for (;;) {
                int v = __hip_atomic_load(&fl[l & 31], __ATOMIC_RELAXED,
                                          __HIP_MEMORY_SCOPE_AGENT);
                if (__ballot(v != 0) == ~0ull) break;
                __builtin_amdgcn_s_sleep(1);
            }
            asm volatile("" ::: "memory");   // no hoisting of h loads above poll
        }

        // ---- h-part: h via cache-bypassing atomic loads, W from LDS ----
        const u16* ah = hbuf + ((size_t)((t & 1) * 2 + dir) * B_ + bg * 16 + lm) * HSZ + lq * 8;
#pragma unroll
        for (int kb = 0; kb < 16; ++kb) {
            union { u64 q[2]; short8 s8; } u;
            const u64* hp = (const u64*)(ah + kb * 32);
            u.q[0] = __hip_atomic_load(hp + 0, __ATOMIC_RELAXED, __HIP_MEMORY_SCOPE_AGENT);
            u.q[1] = __hip_atomic_load(hp + 1, __ATOMIC_RELAXED, __HIP_MEMORY_SCOPE_AGENT);
            short8 a  = u.s8;
            short8 w0 = *(const short8*)&wlds[(0 * 16 + kb) * 512 + l * 8];
            short8 w1 = *(const short8*)&wlds[(1 * 16 + kb) * 512 + l * 8];
            short8 w2 = *(const short8*)&wlds[(2 * 16 + kb) * 512 + l * 8];
            short8 w3 = *(const short8*)&wlds[(3 * 16 + kb) * 512 + l * 8];
            acc0 = __builtin_amdgcn_mfma_f32_16x16x32_bf16(a, w0, acc0, 0, 0, 0);
            acc1 = __builtin_amdgcn_mfma_f32_16x16x32_bf16(a, w1, acc1, 0, 0, 0);
            acc2 = __builtin_amdgcn_mfma_f32_16x16x32_bf16(a, w2, acc2, 0, 0, 0);
            acc3 = __builtin_amdgcn_mfma_f32_16x16x32_bf16(a, w3, acc3, 0, 0, 0);
        }

        // ---- cell update: lane l owns batches bg*16+lq*4+r, hid = c*16+lm ----
        u16* hw = hbuf + ((size_t)(((t + 1) & 1) * 2 + dir) * B_) * HSZ;
        float hv[4];
#pragma unroll
        for (int r = 0; r < 4; ++r) {
            float fg = acc0[r] + Bf;
            float ig = acc1[r] + Bi;
            float og = acc2[r] + Bo;
            float gg = acc3[r] + Bg;
            float cn = sigmoidf_(fg) * cst[r] + sigmoidf_(ig) * tanhf_(gg);
            float hn = sigmoidf_(og) * tanhf_(cn);
            cst[r] = cn;
            hv[r] = hn;
            // write-through atomic store (no cache maintenance)
            __hip_atomic_store(&hw[(size_t)(bg * 16 + lq * 4 + r) * HSZ + hid],
                               f2bf(hn), __ATOMIC_RELAXED, __HIP_MEMORY_SCOPE_AGENT);
        }

        // ---- order h stores before flag store: explicit vmcnt drain ----
        asm volatile("s_waitcnt vmcnt(0)" ::: "memory");
        if (l == 0)
            __hip_atomic_store(&flags[((size_t)chain * S_ + t) * 32 + c], 1,
                               __ATOMIC_RELAXED, __HIP_MEMORY_SCOPE_AGENT);

        // ---- deferred output (off critical path; plain stores) ----
#pragma unroll
        for (int r = 0; r < 4; ++r) {
            const int b = bg * 16 + lq * 4 + r;
            const size_t oidx = ((size_t)b * S_ + tx) * HSZ + hid;
            if (dir == 0) out[oidx] = 0.5f * hv[r];
            else          stage[oidx] = f2bf(hv[r]);
        }
    }
}

// out[i] += 0.5 * bf16(stage[i]); 4 elems/thread
__global__ __launch_bounds__(256) void combine(float* __restrict__ out,
                                               const u16* __restrict__ stage) {
    int i = (blockIdx.x * 256 + threadIdx.x) * 4;   // over 16,777,216
    ushort4 s = *(const ushort4*)(stage + i);
    float4 o = *(float4*)(out + i);
    o.x += 0.5f * __uint_as_float((uint32_t)s.x << 16);
    o.y += 0.5f * __uint_as_float((uint32_t)s.y << 16);
    o.z += 0.5f * __uint_as_float((uint32_t)s.z << 16);
    o.w += 0.5f * __uint_as_float((uint32_t)s.w << 16);
    *(float4*)(out + i) = o;
}

extern "C" void kernel_launch(void* const* d_in, const int* in_sizes, int n_in,
                              void* d_out, int out_size, void* d_ws, size_t ws_size,
                              hipStream_t stream) {
    const float* x  = (const float*)d_in[0];
    const float* Wf = (const float*)d_in[1];
    const float* bf = (const float*)d_in[2];
    const float* Wb = (const float*)d_in[3];
    const float* bb = (const float*)d_in[4];
    float* out = (float*)d_out;
    char* ws = (char*)d_ws;

    u16*   wpack = (u16*)(ws + OFF_WPACK);
    u16*   xb    = (u16*)(ws + OFF_XB);
    u16*   hbuf  = (u16*)(ws + OFF_HB);
    int*   flags = (int*)(ws + OFF_FLAGS);
    u16*   stage = (u16*)(ws + OFF_STAGE);

    // zero h parity buffers + flags (contiguous)
    (void)hipMemsetAsync(ws + OFF_HB, 0, 262144 + 524288, stream);

    pack_w<<<dim3(6144, 2), 256, 0, stream>>>(Wf, Wb, wpack);
    pack_x<<<dim3(32768), 256, 0, stream>>>(x, xb);

    bilstm_persistent<<<dim3(256), dim3(64), 0, stream>>>(
        wpack, xb, hbuf, flags, bf, bb, out, stage);

    combine<<<dim3(16384), 256, 0, stream>>>(out, stage);
}